// Round 4
// baseline (234.171 us; speedup 1.0000x reference)
//
#include <hip/hip_runtime.h>

#define BB 64
#define SS 512
#define HH 768
#define EE 128
#define TT 4
#define NP (EE * TT)           // 512 pairs
#define H4 (HH / 4)            // 192 float4 per row
#define NF4_ROWS (BB * SS * H4)  // 6,291,456 float4 in enhanced
#define NF4_EE (BB * EE * H4)    // 1,572,864 float4 in ee
#define TPB 256
#define PART2_BLKS (NF4_EE / TPB)        // 6144 (ee part, 1 f4/thread)
#define PART1_BLKS (NF4_ROWS / (TPB * 4))  // 6144 (rows part, 4 f4/thread)

typedef float vf4 __attribute__((ext_vector_type(4)));

// ---------------------------------------------------------------------------
// Kernel 1: counting-sort ent_tokens by token position s -> offsets[S+1],
// entries[512] (entity index per pair, duplicates preserved). 1 block, ~3 us.
// Rebuilt every launch (d_ws is re-poisoned).
// ---------------------------------------------------------------------------
__global__ __launch_bounds__(SS) void build_index_kernel(
    const int* __restrict__ ent_tokens, int* __restrict__ offsets,
    int* __restrict__ entries) {
  __shared__ int cnt[SS];
  __shared__ int scan[SS];
  __shared__ int pos[SS];
  const int tid = threadIdx.x;

  cnt[tid] = 0;
  __syncthreads();
  const int s = ent_tokens[tid];
  atomicAdd(&cnt[s], 1);
  __syncthreads();

  scan[tid] = cnt[tid];
  __syncthreads();
  for (int off = 1; off < SS; off <<= 1) {
    int add = (tid >= off) ? scan[tid - off] : 0;
    __syncthreads();
    scan[tid] += add;
    __syncthreads();
  }

  const int excl = scan[tid] - cnt[tid];
  offsets[tid] = excl;
  if (tid == 0) offsets[SS] = NP;
  pos[tid] = excl;
  __syncthreads();

  const int p = atomicAdd(&pos[s], 1);
  entries[p] = tid >> 2;  // entity index e
}

// ---------------------------------------------------------------------------
// Kernel 2: fused streaming kernel, no LDS, no barriers.
//   blocks [0, PART2_BLKS):  ee[b,e,col] -- 1 float4/thread, 4 independent
//                            hidden loads (the 4 token rows).
//   blocks [PART2_BLKS, +PART1_BLKS): enhanced[idx] = hidden[idx] + delta,
//                            4 float4/thread at blockDim stride.
// Match lists come from the global index (L1/L2-hot, ~4 KB total).
// ---------------------------------------------------------------------------
__global__ __launch_bounds__(TPB) void fused_kernel(
    const float* __restrict__ hidden,      // (B,S,H)
    const int* __restrict__ entity_types,  // (B,E)
    const float* __restrict__ conf,        // (B,E)
    const int* __restrict__ ent_tokens,    // (E,T)
    const float* __restrict__ type_table,  // (5,H)
    const float* __restrict__ conf_w,      // (H)
    const float* __restrict__ conf_b,      // (H)
    const int* __restrict__ offsets,       // (S+1)
    const int* __restrict__ entries,       // (NP)
    float* __restrict__ enhanced,          // (B,S,H)
    float* __restrict__ ee) {              // (B,E,H)
  const int tid = threadIdx.x;

  if (blockIdx.x < PART2_BLKS) {
    // ---------------- ee part ----------------
    const int idx = blockIdx.x * TPB + tid;  // float4 index into ee
    const int be = idx / H4;                 // b*EE + e
    const int col = idx - be * H4;
    const int b = be >> 7;
    const int e = be & (EE - 1);
    const int bE = b * EE;

    const int4 tok = ((const int4*)ent_tokens)[e];  // 4 token rows, one load
    const float* hb = hidden + (size_t)b * SS * HH;
    // 4 independent HBM loads in flight.
    const float4 h0 = ((const float4*)(hb + (size_t)tok.x * HH))[col];
    const float4 h1 = ((const float4*)(hb + (size_t)tok.y * HH))[col];
    const float4 h2 = ((const float4*)(hb + (size_t)tok.z * HH))[col];
    const float4 h3 = ((const float4*)(hb + (size_t)tok.w * HH))[col];
    const float4 wv = ((const float4*)conf_w)[col];
    const float4 bv = ((const float4*)conf_b)[col];

    float4 acc;
    acc.x = (h0.x + h1.x) + (h2.x + h3.x);
    acc.y = (h0.y + h1.y) + (h2.y + h3.y);
    acc.z = (h0.z + h1.z) + (h2.z + h3.z);
    acc.w = (h0.w + h1.w) + (h2.w + h3.w);

    const int toks[TT] = {tok.x, tok.y, tok.z, tok.w};
#pragma unroll
    for (int t = 0; t < TT; ++t) {
      const int s = toks[t];
      const int o0 = offsets[s];
      const int o1 = offsets[s + 1];
      for (int j = o0; j < o1; ++j) {
        const int ei = entries[j];
        const int ty = entity_types[bE + ei];
        const float c = conf[bE + ei];
        const float4 tv = ((const float4*)(type_table + (size_t)ty * HH))[col];
        acc.x += tv.x + fmaf(c, wv.x, bv.x);
        acc.y += tv.y + fmaf(c, wv.y, bv.y);
        acc.z += tv.z + fmaf(c, wv.z, bv.z);
        acc.w += tv.w + fmaf(c, wv.w, bv.w);
      }
    }

    vf4 o;
    o.x = acc.x * 0.25f;
    o.y = acc.y * 0.25f;
    o.z = acc.z * 0.25f;
    o.w = acc.w * 0.25f;
    __builtin_nontemporal_store(o, (vf4*)ee + idx);
  } else {
    // ---------------- enhanced part ----------------
    const int base = (blockIdx.x - PART2_BLKS) * (TPB * 4) + tid;
    float4 hv[4];
    int rows[4], cols[4];
#pragma unroll
    for (int j = 0; j < 4; ++j) {
      const int idx = base + TPB * j;
      rows[j] = idx / H4;
      cols[j] = idx - rows[j] * H4;
      hv[j] = ((const float4*)hidden)[idx];  // 4 independent HBM loads
    }
#pragma unroll
    for (int j = 0; j < 4; ++j) {
      const int idx = base + TPB * j;
      const int r = rows[j];
      const int col = cols[j];
      const int b = r >> 9;
      const int s = r & (SS - 1);
      const int bE = b * EE;

      float4 acc = hv[j];
      const int o0 = offsets[s];
      const int o1 = offsets[s + 1];
      if (o1 > o0) {
        const float4 wv = ((const float4*)conf_w)[col];
        const float4 bv = ((const float4*)conf_b)[col];
        for (int m = o0; m < o1; ++m) {
          const int ei = entries[m];
          const int ty = entity_types[bE + ei];
          const float c = conf[bE + ei];
          const float4 tv =
              ((const float4*)(type_table + (size_t)ty * HH))[col];
          acc.x += tv.x + fmaf(c, wv.x, bv.x);
          acc.y += tv.y + fmaf(c, wv.y, bv.y);
          acc.z += tv.z + fmaf(c, wv.z, bv.z);
          acc.w += tv.w + fmaf(c, wv.w, bv.w);
        }
      }
      vf4 ov;
      ov.x = acc.x;
      ov.y = acc.y;
      ov.z = acc.z;
      ov.w = acc.w;
      __builtin_nontemporal_store(ov, (vf4*)enhanced + idx);
    }
  }
}

extern "C" void kernel_launch(void* const* d_in, const int* in_sizes, int n_in,
                              void* d_out, int out_size, void* d_ws,
                              size_t ws_size, hipStream_t stream) {
  const float* hidden = (const float*)d_in[0];
  const int* entity_types = (const int*)d_in[1];
  const float* conf = (const float*)d_in[2];
  const int* ent_tokens = (const int*)d_in[3];
  const float* type_table = (const float*)d_in[4];
  const float* conf_w = (const float*)d_in[5];
  const float* conf_b = (const float*)d_in[6];

  float* enhanced = (float*)d_out;                   // (B,S,H)
  float* ee = (float*)d_out + (size_t)BB * SS * HH;  // (B,E,H)

  int* offsets = (int*)d_ws;          // S+1
  int* entries = offsets + (SS + 1);  // NP

  build_index_kernel<<<1, SS, 0, stream>>>(ent_tokens, offsets, entries);
  fused_kernel<<<PART2_BLKS + PART1_BLKS, TPB, 0, stream>>>(
      hidden, entity_types, conf, ent_tokens, type_table, conf_w, conf_b,
      offsets, entries, enhanced, ee);
}